// Round 18
// baseline (192.188 us; speedup 1.0000x reference)
//
#include <hip/hip_runtime.h>
#include <math.h>
#include <type_traits>

constexpr int DM = 1024;
constexpr int NH = 16;
constexpr int HD = 64;
constexpr int LDQ = 3072;  // fused qkv row stride
constexpr int SPLIT_ST = 38;   // strips >= this are kv-split into 2 blocks
constexpr int PENT = 4224;     // floats per partial entry: 64x64 O + m[64] + l[64]

typedef __attribute__((ext_vector_type(8))) short bf16x8;
typedef __attribute__((ext_vector_type(4))) float f32x4;

__device__ __forceinline__ unsigned short f2bf(float f) {
    union { float f; unsigned u; } v; v.f = f;
    unsigned r = v.u + 0x7FFFu + ((v.u >> 16) & 1u);
    return (unsigned short)(r >> 16);
}
__device__ __forceinline__ float bf2f(unsigned short h) {
    union { unsigned u; float f; } v; v.u = ((unsigned)h) << 16;
    return v.f;
}
__device__ __forceinline__ void gload16(const unsigned short* g, unsigned short* lds) {
    __builtin_amdgcn_global_load_lds(
        (const __attribute__((address_space(1))) unsigned int*)g,
        (__attribute__((address_space(3))) unsigned int*)lds, 16, 0, 0);
}
__device__ __forceinline__ unsigned cvt_pk_bf16(float lo, float hi) {
    unsigned r;
    asm("v_cvt_pk_bf16_f32 %0, %1, %2" : "=v"(r) : "v"(lo), "v"(hi));
    return r;
}
#define MFMA_BF16(a, b, c) __builtin_amdgcn_mfma_f32_16x16x32_bf16(a, b, c, 0, 0, 0)

// In-register P redistribution (T12), validated rounds 4-16.
// NOTE: permlane*_swap with EQUAL inputs is refuted on HW (r9/r15 NaN —
// compiler coalesces the two copies into one register). pack_swap is safe:
// its two inputs are distinct values -> distinct registers.
__device__ __forceinline__ bf16x8 pack_swap(const f32x4& s0, const f32x4& s1) {
    unsigned c00 = cvt_pk_bf16(s0[0], s0[1]);
    unsigned c01 = cvt_pk_bf16(s0[2], s0[3]);
    unsigned c10 = cvt_pk_bf16(s1[0], s1[1]);
    unsigned c11 = cvt_pk_bf16(s1[2], s1[3]);
    asm("v_permlane32_swap_b32 %0, %1" : "+v"(c00), "+v"(c10));
    asm("v_permlane16_swap_b32 %0, %1" : "+v"(c00), "+v"(c10));
    asm("v_permlane32_swap_b32 %0, %1" : "+v"(c01), "+v"(c11));
    asm("v_permlane16_swap_b32 %0, %1" : "+v"(c01), "+v"(c11));
    union { unsigned u[4]; bf16x8 b; } r;
    r.u[0] = c00; r.u[1] = c01; r.u[2] = c10; r.u[3] = c11;
    return r.b;
}

// ---------------------------------------------------------------------------
// fp32 -> bf16 conversion of x and the 4 weights into one flat bf16 region.
// ---------------------------------------------------------------------------
__global__ __launch_bounds__(256)
void convert_bf16(const float* __restrict__ x, const float* __restrict__ wq,
                  const float* __restrict__ wk, const float* __restrict__ wv,
                  const float* __restrict__ wo, unsigned short* __restrict__ dst,
                  long long xElems) {
    const long long W = (long long)DM * DM;
    long long base = ((long long)blockIdx.x * 256 + threadIdx.x) * 8;
    const float* src; long long off;
    if (base < xElems) { src = x; off = base; }
    else {
        long long r = base - xElems;
        int wi = (int)(r / W); off = r - (long long)wi * W;
        src = wi == 0 ? wq : wi == 1 ? wk : wi == 2 ? wv : wo;
    }
    float4 a = *reinterpret_cast<const float4*>(src + off);
    float4 b = *reinterpret_cast<const float4*>(src + off + 4);
    uint4 o;
    o.x = (unsigned)f2bf(a.x) | ((unsigned)f2bf(a.y) << 16);
    o.y = (unsigned)f2bf(a.z) | ((unsigned)f2bf(a.w) << 16);
    o.z = (unsigned)f2bf(b.x) | ((unsigned)f2bf(b.y) << 16);
    o.w = (unsigned)f2bf(b.z) | ((unsigned)f2bf(b.w) << 16);
    *reinterpret_cast<uint4*>(dst + base) = o;
}

// ---------------------------------------------------------------------------
// bf16 MFMA GEMM: C[M][N] = A[M][K] * B[N][K]^T. 128x128 tile, BK=32, 4 waves.
// T1 XCD-chunked block swizzle (validated r16). DoRope: fuse RoPE into the
// epilogue for cols < 2048 (q,k): pairs (d, d+32) live in the same thread as
// acc[m][n] / acc[m][n+2]; q cols additionally scaled by log2(e)/8.
// ---------------------------------------------------------------------------
template <typename OT, bool DoRope>
__global__ __launch_bounds__(256)
void gemm_bf16(const unsigned short* __restrict__ A, const unsigned short* __restrict__ B,
               OT* __restrict__ C, int M, int N, int K) {
    constexpr int BK = 32;
    __shared__ unsigned short As[128 * BK];
    __shared__ unsigned short Bs[128 * BK];
    const int t = threadIdx.x;
    const int w = t >> 6, l = t & 63;
    const int lg = l >> 4, ln = l & 15;

    const int nx = gridDim.x;
    const int nwg = gridDim.x * gridDim.y;
    int wg = blockIdx.y * nx + blockIdx.x;
    wg = (wg & 7) * (nwg >> 3) + (wg >> 3);
    const int bm = (wg / nx) * 128, bn = (wg % nx) * 128;
    const int wr = (w >> 1) * 64, wc = (w & 1) * 64;

    const int li0 = t, li1 = 256 + t;
    const int r0 = li0 >> 2, c0 = (li0 & 3) ^ ((r0 >> 1) & 3);
    const int r1 = li1 >> 2, c1 = (li1 & 3) ^ ((r1 >> 1) & 3);
    const unsigned short* gA0 = A + (size_t)(bm + r0) * K + c0 * 8;
    const unsigned short* gA1 = A + (size_t)(bm + r1) * K + c1 * 8;
    const unsigned short* gB0 = B + (size_t)(bn + r0) * K + c0 * 8;
    const unsigned short* gB1 = B + (size_t)(bn + r1) * K + c1 * 8;
    unsigned short* lA0 = As + (size_t)(w * 64) * 8;
    unsigned short* lA1 = As + (size_t)(256 + w * 64) * 8;
    unsigned short* lB0 = Bs + (size_t)(w * 64) * 8;
    unsigned short* lB1 = Bs + (size_t)(256 + w * 64) * 8;

    int aoff[4], boff[4];  // BYTE offsets
#pragma unroll
    for (int m = 0; m < 4; ++m) { int R = wr + m * 16 + ln; aoff[m] = R * 64 + ((lg ^ ((R >> 1) & 3)) * 16); }
#pragma unroll
    for (int n = 0; n < 4; ++n) { int R = wc + n * 16 + ln; boff[n] = R * 64 + ((lg ^ ((R >> 1) & 3)) * 16); }

    const f32x4 z4 = {0.f, 0.f, 0.f, 0.f};
    f32x4 acc[4][4];
#pragma unroll
    for (int m = 0; m < 4; ++m)
#pragma unroll
        for (int n = 0; n < 4; ++n) acc[m][n] = z4;

    for (int k0 = 0; k0 < K; k0 += BK) {
        __syncthreads();
        gload16(gA0 + k0, lA0);
        gload16(gA1 + k0, lA1);
        gload16(gB0 + k0, lB0);
        gload16(gB1 + k0, lB1);
        __syncthreads();
        bf16x8 af[4], bfr[4];
#pragma unroll
        for (int m = 0; m < 4; ++m) af[m] = *(const bf16x8*)((const char*)As + aoff[m]);
#pragma unroll
        for (int n = 0; n < 4; ++n) bfr[n] = *(const bf16x8*)((const char*)Bs + boff[n]);
#pragma unroll
        for (int m = 0; m < 4; ++m)
#pragma unroll
            for (int n = 0; n < 4; ++n)
                acc[m][n] = MFMA_BF16(af[m], bfr[n], acc[m][n]);
    }

    if constexpr (DoRope) {
        // cols [bn+wc, bn+wc+64) form one head block; rope if col < 2048.
        if (bn + wc < 2048) {
            const float scq = (bn + wc < 1024) ? 0.18033688011112042f : 1.0f;
#pragma unroll
            for (int n = 0; n < 2; ++n) {
                const int jj = n * 16 + ln;                 // d in [0,32)
                const float invf = exp2f(-(float)jj * (13.287712379549449f / 32.0f));
#pragma unroll
                for (int m = 0; m < 4; ++m)
#pragma unroll
                    for (int rg = 0; rg < 4; ++rg) {
                        const int row = bm + wr + m * 16 + lg * 4 + rg;  // l
                        float s, c;
                        sincosf((float)row * invf, &s, &c);
                        const float a = acc[m][n][rg];
                        const float b = acc[m][n + 2][rg];
                        acc[m][n][rg]     = (a * c - b * s) * scq;
                        acc[m][n + 2][rg] = (b * c + a * s) * scq;
                    }
            }
        }
    }

#pragma unroll
    for (int m = 0; m < 4; ++m)
#pragma unroll
        for (int n = 0; n < 4; ++n)
#pragma unroll
            for (int rg = 0; rg < 4; ++rg) {
                int row = bm + wr + m * 16 + lg * 4 + rg;
                int col = bn + wc + n * 16 + ln;
                if constexpr (std::is_same<OT, float>::value)
                    C[(size_t)row * N + col] = acc[m][n][rg];
                else
                    C[(size_t)row * N + col] = f2bf(acc[m][n][rg]);
            }
}

// ---------------------------------------------------------------------------
// One-shot V transpose: vt[h][d][l] = v[l][h*64+d]. Block = 64 l-rows x head.
// ---------------------------------------------------------------------------
__global__ __launch_bounds__(256)
void transp_v(const unsigned short* __restrict__ qkv, unsigned short* __restrict__ vt,
              int L) {
    __shared__ unsigned LT[64][33];
    const int l0 = blockIdx.x * 64;
    const int h = blockIdx.y;
    const int t = threadIdx.x;
    const int jj = t >> 3;   // l-pair 0..31
    const int dc = t & 7;    // d-octet
    const unsigned short* vrow = qkv + 2 * DM + (size_t)(l0 + 2 * jj) * LDQ + h * HD + dc * 8;
    uint4 a = *reinterpret_cast<const uint4*>(vrow);
    uint4 b = *reinterpret_cast<const uint4*>(vrow + LDQ);
    const unsigned aw[4] = {a.x, a.y, a.z, a.w};
    const unsigned bw[4] = {b.x, b.y, b.z, b.w};
#pragma unroll
    for (int e = 0; e < 4; ++e) {
        LT[dc * 8 + e * 2][jj]     = __builtin_amdgcn_perm(bw[e], aw[e], 0x05040100u);
        LT[dc * 8 + e * 2 + 1][jj] = __builtin_amdgcn_perm(bw[e], aw[e], 0x07060302u);
    }
    __syncthreads();
#pragma unroll
    for (int it = 0; it < 2; ++it) {
        const int aidx = it * 256 + t;       // 0..511
        const int d = aidx >> 3, c = aidx & 7;
        uint4 o;
        o.x = LT[d][c * 4];     o.y = LT[d][c * 4 + 1];
        o.z = LT[d][c * 4 + 2]; o.w = LT[d][c * 4 + 3];
        *reinterpret_cast<uint4*>(vt + ((size_t)h * 64 + d) * L + l0 + c * 8) = o;
    }
}

// ---------------------------------------------------------------------------
// bf16 MFMA causal flash attention, single-buffered high-occupancy variant
// (r14/r16, validated at 80us / occ 33%). 90-job/head kv-split decomposition;
// block = 4 waves, wave owns 16 q-rows; XCD-pinned heads; LDS 20,992 B.
// Softmax reduces via __shfl_xor (validated).
// ---------------------------------------------------------------------------
__global__ __launch_bounds__(256)
void attn_mfma(const unsigned short* __restrict__ qkv,
               const unsigned short* __restrict__ vt,
               unsigned short* __restrict__ ob,
               float* __restrict__ pbuf, int L) {
    __shared__ unsigned short Ks[4096];
    __shared__ unsigned short Vs[4096];
    __shared__ unsigned short Ps[32 * 72];

    const int bid = blockIdx.x;
    const int xcd = bid & 7, rest = bid >> 3;
    const int h = xcd + 8 * (rest & 1);
    const int j = rest >> 1;                           // 0..89
    int st, klo, khi;
    if (j < 6)       { st = 37 - j;        klo = 0;  khi = st + 1; }
    else if (j < 32) { st = 38 + (j - 6);  klo = 0;  khi = 32; }
    else if (j < 58) { st = 63 - (j - 32); klo = 32; khi = st + 1; }
    else             { st = 31 - (j - 58); klo = 0;  khi = st + 1; }
    const bool partial = (j >= 6 && j < 58);
    const int part = (j < 32) ? 0 : 1;
    const int q0 = st * 64;

    const int t = threadIdx.x, w = t >> 6, l = t & 63;
    const int lg = l >> 4, ln = l & 15;

    // staging: running pointers, 2 chunks each for K and V per thread
    const unsigned short* kc[2];
    const unsigned short* vc[2];
    int ldso[2];
#pragma unroll
    for (int i = 0; i < 2; ++i) {
        const int pc = t + 256 * i;
        const int r = pc >> 3, cc = (pc & 7) ^ (r & 7);
        kc[i] = qkv + DM + (size_t)(klo * 64 + r) * LDQ + h * HD + cc * 8;  // K rows
        vc[i] = vt + ((size_t)h * 64 + r) * L + klo * 64 + cc * 8;          // V^T rows
        ldso[i] = pc * 8;
    }

    // fragment read byte-offsets (K and V^T: 128B rows, XOR swizzle)
    int foff[4][2];
#pragma unroll
    for (int n = 0; n < 4; ++n)
#pragma unroll
        for (int ks = 0; ks < 2; ++ks) {
            const int R = n * 16 + ln;
            foff[n][ks] = R * 128 + (((ks * 4 + lg) ^ (R & 7)) * 16);
        }
    const int prow2 = ((w & 1) * 16 + ln) * 144;   // epilogue half-pass row

    const f32x4 z4 = {0.f, 0.f, 0.f, 0.f};

    // Q fragments in registers (B-operand of swapped QK^T)
    bf16x8 qf[2];
#pragma unroll
    for (int ks = 0; ks < 2; ++ks)
        qf[ks] = *reinterpret_cast<const bf16x8*>(
            qkv + (size_t)(q0 + w * 16 + ln) * LDQ + h * HD + ks * 32 + lg * 8);

    f32x4 oa[4];
#pragma unroll
    for (int dn = 0; dn < 4; ++dn) oa[dn] = z4;
    float m_i = -INFINITY, l_i = 0.f;

    for (int kt = klo; kt < khi; ++kt) {
        const int kv0 = kt * 64;

        // stage current tile (single buffer)
#pragma unroll
        for (int i = 0; i < 2; ++i) gload16(kc[i], Ks + ldso[i]);
#pragma unroll
        for (int i = 0; i < 2; ++i) gload16(vc[i], Vs + ldso[i]);
#pragma unroll
        for (int i = 0; i < 2; ++i) { kc[i] += (size_t)64 * LDQ; vc[i] += 64; }

        asm volatile("s_waitcnt vmcnt(0)" ::: "memory");
        __builtin_amdgcn_sched_barrier(0);
        __builtin_amdgcn_s_barrier();
        __builtin_amdgcn_sched_barrier(0);

        // S^T = mfma(K, Q): rows = kv, cols = q (Q pre-scaled by log2e/8)
        bf16x8 kf[4][2];
#pragma unroll
        for (int n = 0; n < 4; ++n)
#pragma unroll
            for (int ks = 0; ks < 2; ++ks)
                kf[n][ks] = *reinterpret_cast<const bf16x8*>((const char*)Ks + foff[n][ks]);
        f32x4 s[4];
        __builtin_amdgcn_s_setprio(1);
#pragma unroll
        for (int n = 0; n < 4; ++n) {
            f32x4 acc = MFMA_BF16(kf[n][0], qf[0], z4);
            s[n] = MFMA_BF16(kf[n][1], qf[1], acc);
        }
        __builtin_amdgcn_s_setprio(0);

        // causal mask (diagonal tile only)
        if (kv0 + 63 > q0 + w * 16) {
            const int qq = q0 + w * 16 + ln;
#pragma unroll
            for (int n = 0; n < 4; ++n)
#pragma unroll
                for (int rg = 0; rg < 4; ++rg)
                    if (kv0 + n * 16 + lg * 4 + rg > qq) s[n][rg] = -INFINITY;
        }

        // online softmax: lane-local 16 + 2 shfl reduce; defer-max (T13)
        float mx = fmaxf(fmaxf(s[0][0], s[0][1]), fmaxf(s[0][2], s[0][3]));
#pragma unroll
        for (int n = 1; n < 4; ++n)
            mx = fmaxf(mx, fmaxf(fmaxf(s[n][0], s[n][1]),
                                 fmaxf(s[n][2], s[n][3])));
        mx = fmaxf(mx, __shfl_xor(mx, 16));
        mx = fmaxf(mx, __shfl_xor(mx, 32));
        if (__any(mx > m_i + 8.f)) {
            const float mn = fmaxf(m_i, mx);
            const float sc = exp2f(m_i - mn);
            m_i = mn;
            l_i *= sc;
#pragma unroll
            for (int dn = 0; dn < 4; ++dn) oa[dn] *= sc;
        }
        float ps = 0.f;
#pragma unroll
        for (int n = 0; n < 4; ++n)
#pragma unroll
            for (int rg = 0; rg < 4; ++rg) {
                const float pv = __builtin_amdgcn_exp2f(s[n][rg] - m_i);
                s[n][rg] = pv;
                ps += pv;
            }
        ps += __shfl_xor(ps, 16);
        ps += __shfl_xor(ps, 32);
        l_i += ps;

        // P -> PV B-operand fragments, fully in-register (T12)
        bf16x8 pf0 = pack_swap(s[0], s[1]);
        bf16x8 pf1 = pack_swap(s[2], s[3]);

        // O^T += mfma(V^T, P)
        bf16x8 vf[4][2];
#pragma unroll
        for (int dn = 0; dn < 4; ++dn)
#pragma unroll
            for (int ks = 0; ks < 2; ++ks)
                vf[dn][ks] = *reinterpret_cast<const bf16x8*>((const char*)Vs + foff[dn][ks]);
        __builtin_amdgcn_s_setprio(1);
#pragma unroll
        for (int dn = 0; dn < 4; ++dn) {
            oa[dn] = MFMA_BF16(vf[dn][0], pf0, oa[dn]);
            oa[dn] = MFMA_BF16(vf[dn][1], pf1, oa[dn]);
        }
        __builtin_amdgcn_s_setprio(0);

        __builtin_amdgcn_s_barrier();  // all waves done reading before restage
    }

    __syncthreads();
    if (partial) {
        // store unnormalized f32 partial: O [q][d], then m[64], l[64]
        const int sidx = st - SPLIT_ST;
        float* pb = pbuf + (size_t)((sidx * NH + h) * 2 + part) * PENT;
        const int q = w * 16 + ln;
#pragma unroll
        for (int dn = 0; dn < 4; ++dn)
            *reinterpret_cast<f32x4*>(pb + q * 64 + dn * 16 + lg * 4) = oa[dn];
        if (lg == 0) {
            pb[4096 + q] = m_i;
            pb[4160 + q] = l_i;
        }
    } else {
        // normalize, pre-pack, then 2-pass transpose via small Ps
        const float inv = 1.f / l_i;
        uint2 orow[4];
#pragma unroll
        for (int dn = 0; dn < 4; ++dn) {
            f32x4 o = oa[dn] * inv;
            orow[dn] = make_uint2(cvt_pk_bf16(o[0], o[1]), cvt_pk_bf16(o[2], o[3]));
        }
#pragma unroll
        for (int half = 0; half < 2; ++half) {
            if ((w >> 1) == half) {
#pragma unroll
                for (int dn = 0; dn < 4; ++dn)
                    *reinterpret_cast<uint2*>((char*)Ps + prow2 + dn * 32 + lg * 8) =
                        orow[dn];
            }
            __syncthreads();
            {
                const int r = t >> 3, c = (t & 7) * 8;  // 32 rows x 64 cols
                const bf16x8 vv =
                    *reinterpret_cast<const bf16x8*>((const char*)Ps + r * 144 + c * 2);
                *reinterpret_cast<bf16x8*>(
                    ob + (size_t)(q0 + half * 32 + r) * DM + h * HD + c) = vv;
            }
            __syncthreads();
        }
    }
}

// ---------------------------------------------------------------------------
// Merge the two kv-split partials of each (strip, head) into bf16 output.
// ---------------------------------------------------------------------------
__global__ __launch_bounds__(256)
void combine_split(const float* __restrict__ pbuf, unsigned short* __restrict__ ob) {
    const int sidx = blockIdx.x, h = blockIdx.y;
    const float* p0 = pbuf + (size_t)((sidx * NH + h) * 2 + 0) * PENT;
    const float* p1 = pbuf + (size_t)((sidx * NH + h) * 2 + 1) * PENT;
    const int t = threadIdx.x;
    const int q = t >> 2, dg = (t & 3) * 16;
    const float m1 = p0[4096 + q], l1 = p0[4160 + q];
    const float m2 = p1[4096 + q], l2 = p1[4160 + q];
    const float m = fmaxf(m1, m2);
    const float w1 = exp2f(m1 - m), w2 = exp2f(m2 - m);
    const float inv = 1.f / (w1 * l1 + w2 * l2);
    const int q0 = (sidx + SPLIT_ST) * 64;
#pragma unroll
    for (int e = 0; e < 4; ++e) {
        f32x4 a = *reinterpret_cast<const f32x4*>(p0 + q * 64 + dg + e * 4);
        f32x4 b = *reinterpret_cast<const f32x4*>(p1 + q * 64 + dg + e * 4);
        f32x4 o = (a * w1 + b * w2) * inv;
        *reinterpret_cast<uint2*>(ob + (size_t)(q0 + q) * DM + h * HD + dg + e * 4) =
            make_uint2(cvt_pk_bf16(o[0], o[1]), cvt_pk_bf16(o[2], o[3]));
    }
}

extern "C" void kernel_launch(void* const* d_in, const int* in_sizes, int n_in,
                              void* d_out, int out_size, void* d_ws, size_t ws_size,
                              hipStream_t stream) {
    const float* x  = (const float*)d_in[0];
    const float* wq = (const float*)d_in[1];
    const float* wk = (const float*)d_in[2];
    const float* wv = (const float*)d_in[3];
    const float* wo = (const float*)d_in[4];

    const int L = in_sizes[0] / DM;          // 4096
    const size_t NE = (size_t)L * DM;        // 4M
    const size_t W  = (size_t)DM * DM;       // 1M

    unsigned short* xb   = (unsigned short*)d_ws;
    unsigned short* wqb  = xb + NE;          // wq|wk|wv contiguous for fused GEMM
    unsigned short* wob  = wqb + 3 * W;
    unsigned short* qkvb = wob + W;          // [L][3072]
    unsigned short* ab   = qkvb + (size_t)L * LDQ;
    // V^T scratch lives in d_out (8MB of its 16MB); final GEMM overwrites all.
    unsigned short* vtb  = (unsigned short*)d_out;
    // kv-split partials overlay xb|wqb (dead after QKV GEMM): 832*4224 f32 = 13.7MB
    float* pbuf = (float*)d_ws;

    const long long totalConv = (long long)(NE + 4 * W);  // 8M
    convert_bf16<<<dim3((unsigned)(totalConv / 8 / 256)), dim3(256), 0, stream>>>(
        x, wq, wk, wv, wo, xb, (long long)NE);

    // fused q|k|v projection + fused RoPE epilogue: C[L][3072] = x @ W^T
    gemm_bf16<unsigned short, true><<<dim3(LDQ / 128, L / 128), dim3(256), 0, stream>>>(
        xb, wqb, qkvb, L, LDQ, DM);

    transp_v<<<dim3(L / 64, NH), dim3(256), 0, stream>>>(qkvb, vtb, L);

    // kv-split balanced causal attention: all blocks co-resident
    attn_mfma<<<dim3(90 * NH), dim3(256), 0, stream>>>(qkvb, vtb, ab, pbuf, L);

    combine_split<<<dim3(64 - SPLIT_ST, NH), dim3(256), 0, stream>>>(pbuf, ab);

    gemm_bf16<float, false><<<dim3(DM / 128, L / 128), dim3(256), 0, stream>>>(
        ab, wob, (float*)d_out, L, DM, DM);
}

// Round 20
// 155.349 us; speedup vs baseline: 1.2371x; 1.2371x over previous
//
#include <hip/hip_runtime.h>
#include <math.h>
#include <type_traits>

constexpr int DM = 1024;
constexpr int NH = 16;
constexpr int HD = 64;
constexpr int LDQ = 3072;  // fused qkv row stride
constexpr int SPLIT_ST = 38;   // strips >= this are kv-split into 2 blocks
constexpr int PENT = 4224;     // floats per partial entry: 64x64 O + m[64] + l[64]

typedef __attribute__((ext_vector_type(8))) short bf16x8;
typedef __attribute__((ext_vector_type(4))) float f32x4;

__device__ __forceinline__ unsigned short f2bf(float f) {
    union { float f; unsigned u; } v; v.f = f;
    unsigned r = v.u + 0x7FFFu + ((v.u >> 16) & 1u);
    return (unsigned short)(r >> 16);
}
__device__ __forceinline__ float bf2f(unsigned short h) {
    union { unsigned u; float f; } v; v.u = ((unsigned)h) << 16;
    return v.f;
}
__device__ __forceinline__ void gload16(const unsigned short* g, unsigned short* lds) {
    __builtin_amdgcn_global_load_lds(
        (const __attribute__((address_space(1))) unsigned int*)g,
        (__attribute__((address_space(3))) unsigned int*)lds, 16, 0, 0);
}
__device__ __forceinline__ unsigned cvt_pk_bf16(float lo, float hi) {
    unsigned r;
    asm("v_cvt_pk_bf16_f32 %0, %1, %2" : "=v"(r) : "v"(lo), "v"(hi));
    return r;
}
#define MFMA_BF16(a, b, c) __builtin_amdgcn_mfma_f32_16x16x32_bf16(a, b, c, 0, 0, 0)

// In-register P redistribution (T12), validated rounds 4-16.
// NOTE: permlane*_swap with EQUAL inputs is refuted on HW (r9/r15 NaN).
// NOTE (r18): libm sincosf inside the MFMA GEMM epilogue bloats VGPR to 148.
// NOTE (r19): raw s_barrier + asm-vmcnt pattern implicated in a rare
// post-timing divergence -> replaced with __syncthreads() (r20).
__device__ __forceinline__ bf16x8 pack_swap(const f32x4& s0, const f32x4& s1) {
    unsigned c00 = cvt_pk_bf16(s0[0], s0[1]);
    unsigned c01 = cvt_pk_bf16(s0[2], s0[3]);
    unsigned c10 = cvt_pk_bf16(s1[0], s1[1]);
    unsigned c11 = cvt_pk_bf16(s1[2], s1[3]);
    asm("v_permlane32_swap_b32 %0, %1" : "+v"(c00), "+v"(c10));
    asm("v_permlane16_swap_b32 %0, %1" : "+v"(c00), "+v"(c10));
    asm("v_permlane32_swap_b32 %0, %1" : "+v"(c01), "+v"(c11));
    asm("v_permlane16_swap_b32 %0, %1" : "+v"(c01), "+v"(c11));
    union { unsigned u[4]; bf16x8 b; } r;
    r.u[0] = c00; r.u[1] = c01; r.u[2] = c10; r.u[3] = c11;
    return r.b;
}

// ---------------------------------------------------------------------------
// fp32 -> bf16 conversion of x and the 4 weights into one flat bf16 region.
// ---------------------------------------------------------------------------
__global__ __launch_bounds__(256)
void convert_bf16(const float* __restrict__ x, const float* __restrict__ wq,
                  const float* __restrict__ wk, const float* __restrict__ wv,
                  const float* __restrict__ wo, unsigned short* __restrict__ dst,
                  long long xElems) {
    const long long W = (long long)DM * DM;
    long long base = ((long long)blockIdx.x * 256 + threadIdx.x) * 8;
    const float* src; long long off;
    if (base < xElems) { src = x; off = base; }
    else {
        long long r = base - xElems;
        int wi = (int)(r / W); off = r - (long long)wi * W;
        src = wi == 0 ? wq : wi == 1 ? wk : wi == 2 ? wv : wo;
    }
    float4 a = *reinterpret_cast<const float4*>(src + off);
    float4 b = *reinterpret_cast<const float4*>(src + off + 4);
    uint4 o;
    o.x = (unsigned)f2bf(a.x) | ((unsigned)f2bf(a.y) << 16);
    o.y = (unsigned)f2bf(a.z) | ((unsigned)f2bf(a.w) << 16);
    o.z = (unsigned)f2bf(b.x) | ((unsigned)f2bf(b.y) << 16);
    o.w = (unsigned)f2bf(b.z) | ((unsigned)f2bf(b.w) << 16);
    *reinterpret_cast<uint4*>(dst + base) = o;
}

// ---------------------------------------------------------------------------
// bf16 MFMA GEMM: C[M][N] = A[M][K] * B[N][K]^T. 128x128 tile, BK=32, 4 waves.
// T1 XCD-chunked block swizzle (validated r16).
// ---------------------------------------------------------------------------
template <typename OT>
__global__ __launch_bounds__(256)
void gemm_bf16(const unsigned short* __restrict__ A, const unsigned short* __restrict__ B,
               OT* __restrict__ C, int M, int N, int K) {
    constexpr int BK = 32;
    __shared__ unsigned short As[128 * BK];
    __shared__ unsigned short Bs[128 * BK];
    const int t = threadIdx.x;
    const int w = t >> 6, l = t & 63;
    const int lg = l >> 4, ln = l & 15;

    const int nx = gridDim.x;
    const int nwg = gridDim.x * gridDim.y;
    int wg = blockIdx.y * nx + blockIdx.x;
    wg = (wg & 7) * (nwg >> 3) + (wg >> 3);
    const int bm = (wg / nx) * 128, bn = (wg % nx) * 128;
    const int wr = (w >> 1) * 64, wc = (w & 1) * 64;

    const int li0 = t, li1 = 256 + t;
    const int r0 = li0 >> 2, c0 = (li0 & 3) ^ ((r0 >> 1) & 3);
    const int r1 = li1 >> 2, c1 = (li1 & 3) ^ ((r1 >> 1) & 3);
    const unsigned short* gA0 = A + (size_t)(bm + r0) * K + c0 * 8;
    const unsigned short* gA1 = A + (size_t)(bm + r1) * K + c1 * 8;
    const unsigned short* gB0 = B + (size_t)(bn + r0) * K + c0 * 8;
    const unsigned short* gB1 = B + (size_t)(bn + r1) * K + c1 * 8;
    unsigned short* lA0 = As + (size_t)(w * 64) * 8;
    unsigned short* lA1 = As + (size_t)(256 + w * 64) * 8;
    unsigned short* lB0 = Bs + (size_t)(w * 64) * 8;
    unsigned short* lB1 = Bs + (size_t)(256 + w * 64) * 8;

    int aoff[4], boff[4];  // BYTE offsets
#pragma unroll
    for (int m = 0; m < 4; ++m) { int R = wr + m * 16 + ln; aoff[m] = R * 64 + ((lg ^ ((R >> 1) & 3)) * 16); }
#pragma unroll
    for (int n = 0; n < 4; ++n) { int R = wc + n * 16 + ln; boff[n] = R * 64 + ((lg ^ ((R >> 1) & 3)) * 16); }

    const f32x4 z4 = {0.f, 0.f, 0.f, 0.f};
    f32x4 acc[4][4];
#pragma unroll
    for (int m = 0; m < 4; ++m)
#pragma unroll
        for (int n = 0; n < 4; ++n) acc[m][n] = z4;

    for (int k0 = 0; k0 < K; k0 += BK) {
        __syncthreads();
        gload16(gA0 + k0, lA0);
        gload16(gA1 + k0, lA1);
        gload16(gB0 + k0, lB0);
        gload16(gB1 + k0, lB1);
        __syncthreads();
        bf16x8 af[4], bfr[4];
#pragma unroll
        for (int m = 0; m < 4; ++m) af[m] = *(const bf16x8*)((const char*)As + aoff[m]);
#pragma unroll
        for (int n = 0; n < 4; ++n) bfr[n] = *(const bf16x8*)((const char*)Bs + boff[n]);
#pragma unroll
        for (int m = 0; m < 4; ++m)
#pragma unroll
            for (int n = 0; n < 4; ++n)
                acc[m][n] = MFMA_BF16(af[m], bfr[n], acc[m][n]);
    }

#pragma unroll
    for (int m = 0; m < 4; ++m)
#pragma unroll
        for (int n = 0; n < 4; ++n)
#pragma unroll
            for (int rg = 0; rg < 4; ++rg) {
                int row = bm + wr + m * 16 + lg * 4 + rg;
                int col = bn + wc + n * 16 + ln;
                if constexpr (std::is_same<OT, float>::value)
                    C[(size_t)row * N + col] = acc[m][n][rg];
                else
                    C[(size_t)row * N + col] = f2bf(acc[m][n][rg]);
            }
}

// ---------------------------------------------------------------------------
// RoPE in place on fused qkv (q at col 0, k at col 1024).
// Q additionally scaled by log2(e)/8 so attention scores are exp2-ready.
// ---------------------------------------------------------------------------
__global__ __launch_bounds__(512)
void rope_bf16(unsigned short* __restrict__ qkv) {
    constexpr float SCQ = 0.18033688011112042f;  // log2(e)/sqrt(64)
    const int l = blockIdx.x;
    const int j = threadIdx.x & 31, h = threadIdx.x >> 5;
    const float inv = exp2f(-(float)j * (13.287712379549449f / 32.0f));
    const float ang = (float)l * inv;
    float s, c;
    sincosf(ang, &s, &c);
    const size_t base = (size_t)l * LDQ + h * HD + j;
    float a = bf2f(qkv[base]), b = bf2f(qkv[base + 32]);
    qkv[base]      = f2bf((a * c - b * s) * SCQ);
    qkv[base + 32] = f2bf((b * c + a * s) * SCQ);
    a = bf2f(qkv[base + DM]); b = bf2f(qkv[base + DM + 32]);
    qkv[base + DM]      = f2bf(a * c - b * s);
    qkv[base + DM + 32] = f2bf(b * c + a * s);
}

// ---------------------------------------------------------------------------
// One-shot V transpose: vt[h][d][l] = v[l][h*64+d]. Block = 64 l-rows x head.
// ---------------------------------------------------------------------------
__global__ __launch_bounds__(256)
void transp_v(const unsigned short* __restrict__ qkv, unsigned short* __restrict__ vt,
              int L) {
    __shared__ unsigned LT[64][33];
    const int l0 = blockIdx.x * 64;
    const int h = blockIdx.y;
    const int t = threadIdx.x;
    const int jj = t >> 3;   // l-pair 0..31
    const int dc = t & 7;    // d-octet
    const unsigned short* vrow = qkv + 2 * DM + (size_t)(l0 + 2 * jj) * LDQ + h * HD + dc * 8;
    uint4 a = *reinterpret_cast<const uint4*>(vrow);
    uint4 b = *reinterpret_cast<const uint4*>(vrow + LDQ);
    const unsigned aw[4] = {a.x, a.y, a.z, a.w};
    const unsigned bw[4] = {b.x, b.y, b.z, b.w};
#pragma unroll
    for (int e = 0; e < 4; ++e) {
        LT[dc * 8 + e * 2][jj]     = __builtin_amdgcn_perm(bw[e], aw[e], 0x05040100u);
        LT[dc * 8 + e * 2 + 1][jj] = __builtin_amdgcn_perm(bw[e], aw[e], 0x07060302u);
    }
    __syncthreads();
#pragma unroll
    for (int it = 0; it < 2; ++it) {
        const int aidx = it * 256 + t;       // 0..511
        const int d = aidx >> 3, c = aidx & 7;
        uint4 o;
        o.x = LT[d][c * 4];     o.y = LT[d][c * 4 + 1];
        o.z = LT[d][c * 4 + 2]; o.w = LT[d][c * 4 + 3];
        *reinterpret_cast<uint4*>(vt + ((size_t)h * 64 + d) * L + l0 + c * 8) = o;
    }
}

// ---------------------------------------------------------------------------
// bf16 MFMA causal flash attention (r16 structure, r20-hardened barriers).
// 90-job/head kv-split decomposition; block = 4 waves, wave owns 16 q-rows;
// XCD-pinned heads; LDS 20,992 B; single-buffered K/V staged via
// global_load_lds. All barriers are __syncthreads() (full memory semantics).
// ---------------------------------------------------------------------------
__global__ __launch_bounds__(256)
void attn_mfma(const unsigned short* __restrict__ qkv,
               const unsigned short* __restrict__ vt,
               unsigned short* __restrict__ ob,
               float* __restrict__ pbuf, int L) {
    __shared__ unsigned short Ks[4096];
    __shared__ unsigned short Vs[4096];
    __shared__ unsigned short Ps[32 * 72];

    const int bid = blockIdx.x;
    const int xcd = bid & 7, rest = bid >> 3;
    const int h = xcd + 8 * (rest & 1);
    const int j = rest >> 1;                           // 0..89
    int st, klo, khi;
    if (j < 6)       { st = 37 - j;        klo = 0;  khi = st + 1; }
    else if (j < 32) { st = 38 + (j - 6);  klo = 0;  khi = 32; }
    else if (j < 58) { st = 63 - (j - 32); klo = 32; khi = st + 1; }
    else             { st = 31 - (j - 58); klo = 0;  khi = st + 1; }
    const bool partial = (j >= 6 && j < 58);
    const int part = (j < 32) ? 0 : 1;
    const int q0 = st * 64;

    const int t = threadIdx.x, w = t >> 6, l = t & 63;
    const int lg = l >> 4, ln = l & 15;

    // staging: running pointers, 2 chunks each for K and V per thread
    const unsigned short* kc[2];
    const unsigned short* vc[2];
    int ldso[2];
#pragma unroll
    for (int i = 0; i < 2; ++i) {
        const int pc = t + 256 * i;
        const int r = pc >> 3, cc = (pc & 7) ^ (r & 7);
        kc[i] = qkv + DM + (size_t)(klo * 64 + r) * LDQ + h * HD + cc * 8;  // K rows
        vc[i] = vt + ((size_t)h * 64 + r) * L + klo * 64 + cc * 8;          // V^T rows
        ldso[i] = pc * 8;
    }

    // fragment read byte-offsets (K and V^T: 128B rows, XOR swizzle)
    int foff[4][2];
#pragma unroll
    for (int n = 0; n < 4; ++n)
#pragma unroll
        for (int ks = 0; ks < 2; ++ks) {
            const int R = n * 16 + ln;
            foff[n][ks] = R * 128 + (((ks * 4 + lg) ^ (R & 7)) * 16);
        }
    const int prow2 = ((w & 1) * 16 + ln) * 144;   // epilogue half-pass row

    const f32x4 z4 = {0.f, 0.f, 0.f, 0.f};

    // Q fragments in registers (B-operand of swapped QK^T)
    bf16x8 qf[2];
#pragma unroll
    for (int ks = 0; ks < 2; ++ks)
        qf[ks] = *reinterpret_cast<const bf16x8*>(
            qkv + (size_t)(q0 + w * 16 + ln) * LDQ + h * HD + ks * 32 + lg * 8);

    f32x4 oa[4];
#pragma unroll
    for (int dn = 0; dn < 4; ++dn) oa[dn] = z4;
    float m_i = -INFINITY, l_i = 0.f;

    for (int kt = klo; kt < khi; ++kt) {
        const int kv0 = kt * 64;

        // stage current tile (single buffer), then full barrier (drains
        // vmcnt+lgkm with memory semantics)
#pragma unroll
        for (int i = 0; i < 2; ++i) gload16(kc[i], Ks + ldso[i]);
#pragma unroll
        for (int i = 0; i < 2; ++i) gload16(vc[i], Vs + ldso[i]);
#pragma unroll
        for (int i = 0; i < 2; ++i) { kc[i] += (size_t)64 * LDQ; vc[i] += 64; }
        __syncthreads();

        // S^T = mfma(K, Q): rows = kv, cols = q (Q pre-scaled by log2e/8)
        bf16x8 kf[4][2];
#pragma unroll
        for (int n = 0; n < 4; ++n)
#pragma unroll
            for (int ks = 0; ks < 2; ++ks)
                kf[n][ks] = *reinterpret_cast<const bf16x8*>((const char*)Ks + foff[n][ks]);
        f32x4 s[4];
        __builtin_amdgcn_s_setprio(1);
#pragma unroll
        for (int n = 0; n < 4; ++n) {
            f32x4 acc = MFMA_BF16(kf[n][0], qf[0], z4);
            s[n] = MFMA_BF16(kf[n][1], qf[1], acc);
        }
        __builtin_amdgcn_s_setprio(0);

        // causal mask (diagonal tile only)
        if (kv0 + 63 > q0 + w * 16) {
            const int qq = q0 + w * 16 + ln;
#pragma unroll
            for (int n = 0; n < 4; ++n)
#pragma unroll
                for (int rg = 0; rg < 4; ++rg)
                    if (kv0 + n * 16 + lg * 4 + rg > qq) s[n][rg] = -INFINITY;
        }

        // online softmax: lane-local 16 + 2 shfl reduce; defer-max (T13)
        float mx = fmaxf(fmaxf(s[0][0], s[0][1]), fmaxf(s[0][2], s[0][3]));
#pragma unroll
        for (int n = 1; n < 4; ++n)
            mx = fmaxf(mx, fmaxf(fmaxf(s[n][0], s[n][1]),
                                 fmaxf(s[n][2], s[n][3])));
        mx = fmaxf(mx, __shfl_xor(mx, 16));
        mx = fmaxf(mx, __shfl_xor(mx, 32));
        if (__any(mx > m_i + 8.f)) {
            const float mn = fmaxf(m_i, mx);
            const float sc = exp2f(m_i - mn);
            m_i = mn;
            l_i *= sc;
#pragma unroll
            for (int dn = 0; dn < 4; ++dn) oa[dn] *= sc;
        }
        float ps = 0.f;
#pragma unroll
        for (int n = 0; n < 4; ++n)
#pragma unroll
            for (int rg = 0; rg < 4; ++rg) {
                const float pv = __builtin_amdgcn_exp2f(s[n][rg] - m_i);
                s[n][rg] = pv;
                ps += pv;
            }
        ps += __shfl_xor(ps, 16);
        ps += __shfl_xor(ps, 32);
        l_i += ps;

        // P -> PV B-operand fragments, fully in-register (T12)
        bf16x8 pf0 = pack_swap(s[0], s[1]);
        bf16x8 pf1 = pack_swap(s[2], s[3]);

        // O^T += mfma(V^T, P)
        bf16x8 vf[4][2];
#pragma unroll
        for (int dn = 0; dn < 4; ++dn)
#pragma unroll
            for (int ks = 0; ks < 2; ++ks)
                vf[dn][ks] = *reinterpret_cast<const bf16x8*>((const char*)Vs + foff[dn][ks]);
        __builtin_amdgcn_s_setprio(1);
#pragma unroll
        for (int dn = 0; dn < 4; ++dn) {
            oa[dn] = MFMA_BF16(vf[dn][0], pf0, oa[dn]);
            oa[dn] = MFMA_BF16(vf[dn][1], pf1, oa[dn]);
        }
        __builtin_amdgcn_s_setprio(0);

        __syncthreads();  // all waves done reading before restage
    }

    if (partial) {
        // store unnormalized f32 partial: O [q][d], then m[64], l[64]
        const int sidx = st - SPLIT_ST;
        float* pb = pbuf + (size_t)((sidx * NH + h) * 2 + part) * PENT;
        const int q = w * 16 + ln;
#pragma unroll
        for (int dn = 0; dn < 4; ++dn)
            *reinterpret_cast<f32x4*>(pb + q * 64 + dn * 16 + lg * 4) = oa[dn];
        if (lg == 0) {
            pb[4096 + q] = m_i;
            pb[4160 + q] = l_i;
        }
    } else {
        // normalize, pre-pack, then 2-pass transpose via small Ps
        const float inv = 1.f / l_i;
        uint2 orow[4];
#pragma unroll
        for (int dn = 0; dn < 4; ++dn) {
            f32x4 o = oa[dn] * inv;
            orow[dn] = make_uint2(cvt_pk_bf16(o[0], o[1]), cvt_pk_bf16(o[2], o[3]));
        }
#pragma unroll
        for (int half = 0; half < 2; ++half) {
            if ((w >> 1) == half) {
#pragma unroll
                for (int dn = 0; dn < 4; ++dn)
                    *reinterpret_cast<uint2*>((char*)Ps + prow2 + dn * 32 + lg * 8) =
                        orow[dn];
            }
            __syncthreads();
            {
                const int r = t >> 3, c = (t & 7) * 8;  // 32 rows x 64 cols
                const bf16x8 vv =
                    *reinterpret_cast<const bf16x8*>((const char*)Ps + r * 144 + c * 2);
                *reinterpret_cast<bf16x8*>(
                    ob + (size_t)(q0 + half * 32 + r) * DM + h * HD + c) = vv;
            }
            __syncthreads();
        }
    }
}

// ---------------------------------------------------------------------------
// Merge the two kv-split partials of each (strip, head) into bf16 output.
// ---------------------------------------------------------------------------
__global__ __launch_bounds__(256)
void combine_split(const float* __restrict__ pbuf, unsigned short* __restrict__ ob) {
    const int sidx = blockIdx.x, h = blockIdx.y;
    const float* p0 = pbuf + (size_t)((sidx * NH + h) * 2 + 0) * PENT;
    const float* p1 = pbuf + (size_t)((sidx * NH + h) * 2 + 1) * PENT;
    const int t = threadIdx.x;
    const int q = t >> 2, dg = (t & 3) * 16;
    const float m1 = p0[4096 + q], l1 = p0[4160 + q];
    const float m2 = p1[4096 + q], l2 = p1[4160 + q];
    const float m = fmaxf(m1, m2);
    const float w1 = exp2f(m1 - m), w2 = exp2f(m2 - m);
    const float inv = 1.f / (w1 * l1 + w2 * l2);
    const int q0 = (sidx + SPLIT_ST) * 64;
#pragma unroll
    for (int e = 0; e < 4; ++e) {
        f32x4 a = *reinterpret_cast<const f32x4*>(p0 + q * 64 + dg + e * 4);
        f32x4 b = *reinterpret_cast<const f32x4*>(p1 + q * 64 + dg + e * 4);
        f32x4 o = (a * w1 + b * w2) * inv;
        *reinterpret_cast<uint2*>(ob + (size_t)(q0 + q) * DM + h * HD + dg + e * 4) =
            make_uint2(cvt_pk_bf16(o[0], o[1]), cvt_pk_bf16(o[2], o[3]));
    }
}

extern "C" void kernel_launch(void* const* d_in, const int* in_sizes, int n_in,
                              void* d_out, int out_size, void* d_ws, size_t ws_size,
                              hipStream_t stream) {
    const float* x  = (const float*)d_in[0];
    const float* wq = (const float*)d_in[1];
    const float* wk = (const float*)d_in[2];
    const float* wv = (const float*)d_in[3];
    const float* wo = (const float*)d_in[4];

    const int L = in_sizes[0] / DM;          // 4096
    const size_t NE = (size_t)L * DM;        // 4M
    const size_t W  = (size_t)DM * DM;       // 1M

    unsigned short* xb   = (unsigned short*)d_ws;
    unsigned short* wqb  = xb + NE;          // wq|wk|wv contiguous for fused GEMM
    unsigned short* wob  = wqb + 3 * W;
    unsigned short* qkvb = wob + W;          // [L][3072]
    unsigned short* ab   = qkvb + (size_t)L * LDQ;
    // V^T scratch lives in d_out (8MB of its 16MB); final GEMM overwrites all.
    unsigned short* vtb  = (unsigned short*)d_out;
    // kv-split partials overlay xb|wqb (dead after QKV GEMM): 832*4224 f32 = 13.7MB
    float* pbuf = (float*)d_ws;

    const long long totalConv = (long long)(NE + 4 * W);  // 8M
    convert_bf16<<<dim3((unsigned)(totalConv / 8 / 256)), dim3(256), 0, stream>>>(
        x, wq, wk, wv, wo, xb, (long long)NE);

    // fused q|k|v projection: C[L][3072] = x @ [wq;wk;wv]^T
    gemm_bf16<unsigned short><<<dim3(LDQ / 128, L / 128), dim3(256), 0, stream>>>(
        xb, wqb, qkvb, L, LDQ, DM);

    rope_bf16<<<dim3(L), dim3(512), 0, stream>>>(qkvb);

    transp_v<<<dim3(L / 64, NH), dim3(256), 0, stream>>>(qkvb, vtb, L);

    // kv-split balanced causal attention: all blocks co-resident
    attn_mfma<<<dim3(90 * NH), dim3(256), 0, stream>>>(qkvb, vtb, ab, pbuf, L);

    combine_split<<<dim3(64 - SPLIT_ST, NH), dim3(256), 0, stream>>>(pbuf, ab);

    gemm_bf16<float><<<dim3(DM / 128, L / 128), dim3(256), 0, stream>>>(
        ab, wob, (float*)d_out, L, DM, DM);
}